// Round 6
// baseline (224.821 us; speedup 1.0000x reference)
//
#include <hip/hip_runtime.h>
#include <hip/hip_bf16.h>
#include <stdint.h>

typedef unsigned short u16;
typedef short short8 __attribute__((ext_vector_type(8)));
typedef short short4v __attribute__((ext_vector_type(4)));
typedef float floatx4 __attribute__((ext_vector_type(4)));

__device__ __forceinline__ float b2f(u16 v) {
  union { unsigned int u; float f; } c; c.u = ((unsigned int)v) << 16; return c.f;
}
__device__ __forceinline__ u16 f2b(float f) {
  union { float f; unsigned int u; } c; c.f = f;
  unsigned int u = c.u;
  return (u16)((u + 0x7fffu + ((u >> 16) & 1u)) >> 16);  // RNE
}

// async global->LDS, 16B per lane. LDS dest must be wave-uniform base + lane*16.
__device__ __forceinline__ void gld_lds16(const u16* g, u16* l) {
  __builtin_amdgcn_global_load_lds(
      (const __attribute__((address_space(1))) unsigned int*)g,
      (__attribute__((address_space(3))) unsigned int*)l,
      16, 0, 0);
}

// ---------------------------------------------------------------------------
// Fused prep: x fp32->bf16 (blocks 0..6143), w_attn T (6144..6575),
// w_proj T (6576..6719). Transposes also convert fp32->bf16.
// ---------------------------------------------------------------------------
__device__ __forceinline__ void tile_transpose_f2b(
    const float* __restrict__ in, u16* __restrict__ out,
    int inRS, int outRS, int rb, int cb, int tid)
{
  __shared__ __align__(16) u16 t[64][72];
  const int r = tid >> 2, sg = tid & 3;
  const float* ip = in + (long)(rb + r) * inRS + cb + sg * 16;
#pragma unroll
  for (int i = 0; i < 16; i += 4) {
    float4 f = *(const float4*)(ip + i);
    t[r][sg * 16 + i]     = f2b(f.x);
    t[r][sg * 16 + i + 1] = f2b(f.y);
    t[r][sg * 16 + i + 2] = f2b(f.z);
    t[r][sg * 16 + i + 3] = f2b(f.w);
  }
  __syncthreads();
  short8 v0, v1;
#pragma unroll
  for (int i = 0; i < 8; i++) v0[i] = (short)t[sg * 16 + i][r];
#pragma unroll
  for (int i = 0; i < 8; i++) v1[i] = (short)t[sg * 16 + 8 + i][r];
  *(short8*)(out + (long)(cb + r) * outRS + rb + sg * 16)     = v0;
  *(short8*)(out + (long)(cb + r) * outRS + rb + sg * 16 + 8) = v1;
}

__global__ __launch_bounds__(256) void prep(
    const float* __restrict__ x, u16* __restrict__ xb,
    const float* __restrict__ w_attn, u16* __restrict__ wTa,
    const float* __restrict__ w_proj, u16* __restrict__ wTp)
{
  const int bid = blockIdx.x, tid = threadIdx.x;
  if (bid < 6144) {
    int i = (bid * 256 + tid) * 4;
    float4 f = *(const float4*)(x + i);
    short4v v;
    v[0] = (short)f2b(f.x); v[1] = (short)f2b(f.y);
    v[2] = (short)f2b(f.z); v[3] = (short)f2b(f.w);
    *(short4v*)(xb + i) = v;
  } else if (bid < 6576) {
    int t = bid - 6144;                 // 36 x 12 tiles of w_attn [768][2304]
    tile_transpose_f2b(w_attn, wTa, 2304, 768, (t / 36) * 64, (t % 36) * 64, tid);
  } else {
    int t = bid - 6576;                 // 12 x 12 tiles of w_proj [768][768]
    tile_transpose_f2b(w_proj, wTp, 768, 768, (t / 12) * 64, (t % 12) * 64, tid);
  }
}

// ---------------------------------------------------------------------------
// C[M][N] = A[M][K] * Bt[N][K]^T + bias[N]   (A,Bt bf16, fp32 accum)
// BM=128: 2x2 waves of 64x64 (G=4 DMAs/stage). BM=64: 1x4 waves of 64x32 (G=3).
// AITER-style 3-stage pipeline: raw s_barrier + s_waitcnt vmcnt(G) — the
// prefetch for it+2 is never drained by the barrier (never vmcnt(0) in
// steady state), so DMA latency spans a full iteration.
// ---------------------------------------------------------------------------
__device__ __forceinline__ void store_out(u16* p, float v)  { *p = f2b(v); }
__device__ __forceinline__ void store_out(float* p, float v) { *p = v; }

template <int BM>
__device__ __forceinline__ void stage(
    const u16* __restrict__ A, const u16* __restrict__ Bt,
    long rowbase, long colbase, int K, int k0,
    u16* dA, u16* dB, int tid)
{
  const int c0 = tid, c1 = tid + 256;
  const int ar0 = c0 >> 2, ak0 = (c0 & 3) * 8;
  const int ar1 = c1 >> 2, ak1 = (c1 & 3) * 8;
  gld_lds16(A + (rowbase + ar0) * K + k0 + ak0, dA + c0 * 8);
  if (BM == 128)
    gld_lds16(A + (rowbase + ar1) * K + k0 + ak1, dA + c1 * 8);
  gld_lds16(Bt + (colbase + ar0) * K + k0 + ak0, dB + c0 * 8);
  gld_lds16(Bt + (colbase + ar1) * K + k0 + ak1, dB + c1 * 8);
}

// waitcnt imm: vmcnt[3:0] | expcnt(7=nowait)<<4 | lgkmcnt<<8
// vmcnt(4)=0x0074, vmcnt(3)=0x0073, vmcnt(0)=0x0070  (all wait lgkmcnt(0))

template <typename OT, int BM>
__global__ __launch_bounds__(256) void gemm_bt_bias(
    const u16* __restrict__ A, const u16* __restrict__ Bt,
    const float* __restrict__ bias, OT* __restrict__ C,
    int M, int N, int K)
{
  constexpr int WNF = (BM == 128) ? 4 : 2;      // n-frags per wave
  constexpr int G   = (BM == 128) ? 4 : 3;      // DMAs per stage
  __shared__ __align__(16) u16 sA[3][BM * 32];
  __shared__ __align__(16) u16 sB[3][128 * 32];
  const int tid = threadIdx.x;
  const int lane = tid & 63;
  const int wave = tid >> 6;
  const int wm = (BM == 128) ? (wave >> 1) * 64 : 0;
  const int wn = (BM == 128) ? (wave & 1) * 64 : wave * 32;
  const int l15 = lane & 15;
  const int q = lane >> 4;
  const long rowbase = (long)blockIdx.y * BM;
  const long colbase = (long)blockIdx.x * 128;

  floatx4 acc[4][WNF];
#pragma unroll
  for (int i = 0; i < 4; i++)
#pragma unroll
    for (int j = 0; j < WNF; j++) acc[i][j] = (floatx4){0.f, 0.f, 0.f, 0.f};

  const int NIT = K / 32;
  stage<BM>(A, Bt, rowbase, colbase, K, 0,  sA[0], sB[0], tid);
  stage<BM>(A, Bt, rowbase, colbase, K, 32, sA[1], sB[1], tid);
  __builtin_amdgcn_s_waitcnt((BM == 128) ? 0x0074 : 0x0073);  // stage0 retired
  __builtin_amdgcn_s_barrier();

  for (int it = 0; it < NIT; ++it) {
    const int cur = it % 3;
    if (it + 2 < NIT)  // prefetch 2 ahead; its buffer's readers passed the
                       // barrier at end of iter it-1, so overwrite is safe
      stage<BM>(A, Bt, rowbase, colbase, K, (it + 2) * 32, sA[(it + 2) % 3], sB[(it + 2) % 3], tid);

    short8 af[4], bf[WNF];
#pragma unroll
    for (int mt = 0; mt < 4; mt++)
      af[mt] = *(const short8*)(sA[cur] + (wm + mt * 16 + l15) * 32 + q * 8);
#pragma unroll
    for (int nt = 0; nt < WNF; nt++)
      bf[nt] = *(const short8*)(sB[cur] + (wn + nt * 16 + l15) * 32 + q * 8);
#pragma unroll
    for (int mt = 0; mt < 4; mt++)
#pragma unroll
      for (int nt = 0; nt < WNF; nt++)
        acc[mt][nt] = __builtin_amdgcn_mfma_f32_16x16x32_bf16(af[mt], bf[nt], acc[mt][nt], 0, 0, 0);

    if (it + 1 < NIT) {
      // retire stage(it+1) only; stage(it+2) stays in flight across the barrier
      if (it + 2 < NIT)
        __builtin_amdgcn_s_waitcnt((BM == 128) ? 0x0074 : 0x0073);
      else
        __builtin_amdgcn_s_waitcnt(0x0070);
      __builtin_amdgcn_s_barrier();
    }
  }

#pragma unroll
  for (int nt = 0; nt < WNF; nt++) {
    const long col = colbase + wn + nt * 16 + l15;
    const float bv = bias[col];
#pragma unroll
    for (int mt = 0; mt < 4; mt++)
#pragma unroll
      for (int r = 0; r < 4; r++) {
        const long row = rowbase + wm + mt * 16 + q * 4 + r;
        store_out(C + row * N + col, acc[mt][nt][r] + bv);
      }
  }
}

// ---------------------------------------------------------------------------
// Flash attention, causal. One block = (b*12+h, q-tile of 64 rows), 256 thr.
// S^T = K (Q/8)^T formulation: softmax rows live on lane&15 -> in-register
// online softmax (shfl_xor 16/32), no S round-trip, 2 barriers/iter.
// qkv: [8192][2304] bf16 (Q|K|V), y: [8192][768] bf16
// ---------------------------------------------------------------------------
__global__ __launch_bounds__(256) void attn_fwd(
    const u16* __restrict__ qkv, u16* __restrict__ y)
{
  const int bh = blockIdx.x;        // b*12 + h
  const int qt = 15 - blockIdx.y;   // reversed: long blocks dispatch first
  const int b = bh / 12, h = bh % 12;
  const long rowOff = (long)b * 1024;
  const int qb = qt * 64;

  __shared__ __align__(16) u16 sK[64 * 72];
  __shared__ __align__(16) u16 sVs[64 * 72];  // raw V staging [key][d]
  __shared__ __align__(16) u16 sV[64 * 72];   // V^T [d][key]
  __shared__ __align__(16) u16 sP[64 * 72];   // P [qrow][key]

  const int tid = threadIdx.x;
  const int lane = tid & 63, wave = tid >> 6;
  const int l15 = lane & 15, q = lane >> 4;
  const int qrow_g = qb + wave * 16 + l15;    // this lane's softmax row

  // Q fragments in registers, pre-scaled by 1/8 (B-operand: n=l15, k=q*8+j)
  short8 qf[2];
  {
    const u16* qp = qkv + (long)(rowOff + qrow_g) * 2304 + h * 64 + q * 8;
    short8 a0 = *(const short8*)(qp);
    short8 a1 = *(const short8*)(qp + 32);
#pragma unroll
    for (int i = 0; i < 8; i++) {
      a0[i] = (short)f2b(b2f((u16)a0[i]) * 0.125f);
      a1[i] = (short)f2b(b2f((u16)a1[i]) * 0.125f);
    }
    qf[0] = a0; qf[1] = a1;
  }

  float m_i = -1e30f, l_i = 0.f;
  floatx4 o[4];
#pragma unroll
  for (int nt = 0; nt < 4; nt++) o[nt] = (floatx4){0.f, 0.f, 0.f, 0.f};

  for (int j = 0; j <= qt; j++) {
    const int jb = j * 64;
#pragma unroll
    for (int rep = 0; rep < 2; rep++) {
      int idx = tid + rep * 256;
      int r = idx >> 3, ch = (idx & 7) * 8;
      const u16* src = qkv + (long)(rowOff + jb + r) * 2304 + 768 + h * 64 + ch;
      *(short8*)(sK + r * 72 + ch)  = *(const short8*)(src);
      *(short8*)(sVs + r * 72 + ch) = *(const short8*)(src + 768);
    }
    __syncthreads();

    // transpose V: sVs[key][d] -> sV[d][key], packed b64 writes
    {
      int d = tid >> 2, kg = (tid & 3) * 16;
      u16 tmp[16];
#pragma unroll
      for (int i = 0; i < 16; i++) tmp[i] = sVs[(kg + i) * 72 + d];
#pragma unroll
      for (int s = 0; s < 4; s++) {
        short4v vv;
        vv[0] = (short)tmp[s*4]; vv[1] = (short)tmp[s*4+1];
        vv[2] = (short)tmp[s*4+2]; vv[3] = (short)tmp[s*4+3];
        *(short4v*)(sV + d * 72 + kg + s * 4) = vv;
      }
    }

    // S^T = K (Q/8)^T : fragments mt over 16-key blocks
    floatx4 sf[4];
#pragma unroll
    for (int mt = 0; mt < 4; mt++) sf[mt] = (floatx4){0.f, 0.f, 0.f, 0.f};
#pragma unroll
    for (int kk = 0; kk < 2; kk++) {
#pragma unroll
      for (int mt = 0; mt < 4; mt++) {
        short8 kf = *(const short8*)(sK + (mt * 16 + l15) * 72 + kk * 32 + q * 8);
        sf[mt] = __builtin_amdgcn_mfma_f32_16x16x32_bf16(kf, qf[kk], sf[mt], 0, 0, 0);
      }
    }

    // causal mask + in-register online softmax (row = l15-qrow)
    float mx = m_i;
#pragma unroll
    for (int mt = 0; mt < 4; mt++)
#pragma unroll
      for (int r = 0; r < 4; r++) {
        int key_g = jb + mt * 16 + q * 4 + r;
        float v = sf[mt][r];
        if (key_g > qrow_g) v = -1e30f;
        sf[mt][r] = v;
        mx = fmaxf(mx, v);
      }
    mx = fmaxf(mx, __shfl_xor(mx, 16));
    mx = fmaxf(mx, __shfl_xor(mx, 32));
    float al = __expf(m_i - mx);
    m_i = mx;
    float rsum = 0.f;
#pragma unroll
    for (int mt = 0; mt < 4; mt++) {
      short4v pv;
#pragma unroll
      for (int r = 0; r < 4; r++) {
        float p = __expf(sf[mt][r] - mx);
        rsum += p;
        pv[r] = (short)f2b(p);
      }
      *(short4v*)(sP + (wave * 16 + l15) * 72 + mt * 16 + q * 4) = pv;
    }
    rsum += __shfl_xor(rsum, 16);
    rsum += __shfl_xor(rsum, 32);
    l_i = l_i * al + rsum;
    __syncthreads();   // sV + sP visible before PV

    // O = O*alpha + P V   (o rows are q*4+r -> fetch alpha from lane q*4+r)
    float al_r[4];
#pragma unroll
    for (int r = 0; r < 4; r++) al_r[r] = __shfl(al, q * 4 + r);
#pragma unroll
    for (int nt = 0; nt < 4; nt++)
#pragma unroll
      for (int r = 0; r < 4; r++) o[nt][r] *= al_r[r];
#pragma unroll
    for (int kk = 0; kk < 2; kk++) {
      short8 pf = *(const short8*)(sP + (wave * 16 + l15) * 72 + kk * 32 + q * 8);
#pragma unroll
      for (int nt = 0; nt < 4; nt++) {
        short8 vf = *(const short8*)(sV + (nt * 16 + l15) * 72 + kk * 32 + q * 8);
        o[nt] = __builtin_amdgcn_mfma_f32_16x16x32_bf16(pf, vf, o[nt], 0, 0, 0);
      }
    }
  }

  float linv = 1.f / l_i;
  float li_r[4];
#pragma unroll
  for (int r = 0; r < 4; r++) li_r[r] = __shfl(linv, q * 4 + r);
#pragma unroll
  for (int nt = 0; nt < 4; nt++)
#pragma unroll
    for (int r = 0; r < 4; r++) {
      int row = qb + wave * 16 + q * 4 + r;
      int col = h * 64 + nt * 16 + l15;
      y[(rowOff + row) * 768 + col] = f2b(o[nt][r] * li_r[r]);
    }
}

// ---------------------------------------------------------------------------
extern "C" void kernel_launch(void* const* d_in, const int* in_sizes, int n_in,
                              void* d_out, int out_size, void* d_ws, size_t ws_size,
                              hipStream_t stream) {
  const float* x      = (const float*)d_in[0];  // [8192][768] fp32
  const float* w_attn = (const float*)d_in[1];  // [768][2304] fp32
  const float* b_attn = (const float*)d_in[2];  // [2304] fp32
  const float* w_proj = (const float*)d_in[3];  // [768][768] fp32
  const float* b_proj = (const float*)d_in[4];  // [768] fp32
  float* out = (float*)d_out;                   // [8192][768] fp32

  char* ws = (char*)d_ws;
  u16* xb   = (u16*)ws; ws += (size_t)8192 * 768 * 2;    // 12.6 MB
  u16* wTa  = (u16*)ws; ws += (size_t)2304 * 768 * 2;    //  3.5 MB
  u16* wTp  = (u16*)ws; ws += (size_t)768 * 768 * 2;     //  1.2 MB
  u16* qkv  = (u16*)ws; ws += (size_t)8192 * 2304 * 2;   // 37.7 MB
  u16* yatt = (u16*)ws; ws += (size_t)8192 * 768 * 2;    // 12.6 MB

  // fused prep: x->bf16 + both weight transposes
  prep<<<dim3(6720), 256, 0, stream>>>(x, xb, w_attn, wTa, w_proj, wTp);

  // qkv = x @ w_attn + b_attn   (bf16 out, 128x128 tiles)
  gemm_bt_bias<u16, 128><<<dim3(18, 64), 256, 0, stream>>>(xb, wTa, b_attn, qkv, 8192, 2304, 768);

  // flash attention (in-register softmax)
  attn_fwd<<<dim3(96, 16), 256, 0, stream>>>(qkv, yatt);

  // out = yatt @ w_proj + b_proj   (fp32 out, 64x128 tiles -> 768 blocks)
  gemm_bt_bias<float, 64><<<dim3(6, 128), 256, 0, stream>>>(yatt, wTp, b_proj, out, 8192, 768, 768);
}

// Round 7
// 221.150 us; speedup vs baseline: 1.0166x; 1.0166x over previous
//
#include <hip/hip_runtime.h>
#include <hip/hip_bf16.h>
#include <stdint.h>

typedef unsigned short u16;
typedef short short8 __attribute__((ext_vector_type(8)));
typedef short short4v __attribute__((ext_vector_type(4)));
typedef float floatx4 __attribute__((ext_vector_type(4)));

__device__ __forceinline__ float b2f(u16 v) {
  union { unsigned int u; float f; } c; c.u = ((unsigned int)v) << 16; return c.f;
}
__device__ __forceinline__ u16 f2b(float f) {
  union { float f; unsigned int u; } c; c.f = f;
  unsigned int u = c.u;
  return (u16)((u + 0x7fffu + ((u >> 16) & 1u)) >> 16);  // RNE
}

// async global->LDS, 16B per lane. LDS dest must be wave-uniform base + lane*16.
__device__ __forceinline__ void gld_lds16(const u16* g, u16* l) {
  __builtin_amdgcn_global_load_lds(
      (const __attribute__((address_space(1))) unsigned int*)g,
      (__attribute__((address_space(3))) unsigned int*)l,
      16, 0, 0);
}

// ---------------------------------------------------------------------------
// Fused prep: x fp32->bf16 (blocks 0..6143), w_attn T (6144..6575),
// w_proj T (6576..6719). Transposes also convert fp32->bf16.
// ---------------------------------------------------------------------------
__device__ __forceinline__ void tile_transpose_f2b(
    const float* __restrict__ in, u16* __restrict__ out,
    int inRS, int outRS, int rb, int cb, int tid)
{
  __shared__ __align__(16) u16 t[64][72];
  const int r = tid >> 2, sg = tid & 3;
  const float* ip = in + (long)(rb + r) * inRS + cb + sg * 16;
#pragma unroll
  for (int i = 0; i < 16; i += 4) {
    float4 f = *(const float4*)(ip + i);
    t[r][sg * 16 + i]     = f2b(f.x);
    t[r][sg * 16 + i + 1] = f2b(f.y);
    t[r][sg * 16 + i + 2] = f2b(f.z);
    t[r][sg * 16 + i + 3] = f2b(f.w);
  }
  __syncthreads();
  short8 v0, v1;
#pragma unroll
  for (int i = 0; i < 8; i++) v0[i] = (short)t[sg * 16 + i][r];
#pragma unroll
  for (int i = 0; i < 8; i++) v1[i] = (short)t[sg * 16 + 8 + i][r];
  *(short8*)(out + (long)(cb + r) * outRS + rb + sg * 16)     = v0;
  *(short8*)(out + (long)(cb + r) * outRS + rb + sg * 16 + 8) = v1;
}

__global__ __launch_bounds__(256) void prep(
    const float* __restrict__ x, u16* __restrict__ xb,
    const float* __restrict__ w_attn, u16* __restrict__ wTa,
    const float* __restrict__ w_proj, u16* __restrict__ wTp)
{
  const int bid = blockIdx.x, tid = threadIdx.x;
  if (bid < 6144) {
    int i = (bid * 256 + tid) * 4;
    float4 f = *(const float4*)(x + i);
    short4v v;
    v[0] = (short)f2b(f.x); v[1] = (short)f2b(f.y);
    v[2] = (short)f2b(f.z); v[3] = (short)f2b(f.w);
    *(short4v*)(xb + i) = v;
  } else if (bid < 6576) {
    int t = bid - 6144;                 // 36 x 12 tiles of w_attn [768][2304]
    tile_transpose_f2b(w_attn, wTa, 2304, 768, (t / 36) * 64, (t % 36) * 64, tid);
  } else {
    int t = bid - 6576;                 // 12 x 12 tiles of w_proj [768][768]
    tile_transpose_f2b(w_proj, wTp, 768, 768, (t / 12) * 64, (t % 12) * 64, tid);
  }
}

// ---------------------------------------------------------------------------
// C[M][N] = A[M][K] * Bt[N][K]^T + bias[N]   (A,Bt bf16, fp32 accum)
// BM=128: 2x2 waves of 64x64. BM=64: 1x4 waves of 64x32 (BN=128 both).
// Round-5 double-buffer structure (measured best; raw-vmcnt pipeline and
// single-buffer both slower — R4/R6 evidence).
// 1D grid with XCD-aware swizzle: XCD x (= bid%8) owns row-tiles r%8==x,
// sweeping columns fastest -> per-XCD L2 working set = 1 A-strip + full Bt.
// ---------------------------------------------------------------------------
__device__ __forceinline__ void store_out(u16* p, float v)  { *p = f2b(v); }
__device__ __forceinline__ void store_out(float* p, float v) { *p = v; }

template <int BM>
__device__ __forceinline__ void stage(
    const u16* __restrict__ A, const u16* __restrict__ Bt,
    long rowbase, long colbase, int K, int k0,
    u16* dA, u16* dB, int tid)
{
  const int c0 = tid, c1 = tid + 256;
  const int ar0 = c0 >> 2, ak0 = (c0 & 3) * 8;
  const int ar1 = c1 >> 2, ak1 = (c1 & 3) * 8;
  gld_lds16(A + (rowbase + ar0) * K + k0 + ak0, dA + c0 * 8);
  if (BM == 128)
    gld_lds16(A + (rowbase + ar1) * K + k0 + ak1, dA + c1 * 8);
  gld_lds16(Bt + (colbase + ar0) * K + k0 + ak0, dB + c0 * 8);
  gld_lds16(Bt + (colbase + ar1) * K + k0 + ak1, dB + c1 * 8);
}

template <typename OT, int BM>
__global__ __launch_bounds__(256) void gemm_bt_bias(
    const u16* __restrict__ A, const u16* __restrict__ Bt,
    const float* __restrict__ bias, OT* __restrict__ C,
    int M, int N, int K, int NBX)   // NBX = N/128 (col tiles)
{
  constexpr int WNF = (BM == 128) ? 4 : 2;      // n-frags per wave
  __shared__ __align__(16) u16 sA[2][BM * 32];
  __shared__ __align__(16) u16 sB[2][128 * 32];
  const int tid = threadIdx.x;
  const int lane = tid & 63;
  const int wave = tid >> 6;
  const int wm = (BM == 128) ? (wave >> 1) * 64 : 0;
  const int wn = (BM == 128) ? (wave & 1) * 64 : wave * 32;
  const int l15 = lane & 15;
  const int q = lane >> 4;

  // XCD swizzle: bid%8 = xcd (dispatch round-robin heuristic), per-XCD
  // blocks sweep columns fastest over row-tiles r = xcd + 8*g.
  const int bid = blockIdx.x;
  const int xcd = bid & 7, slot = bid >> 3;
  const int bx = slot % NBX;
  const int by = (slot / NBX) * 8 + xcd;
  const long rowbase = (long)by * BM;
  const long colbase = (long)bx * 128;

  floatx4 acc[4][WNF];
#pragma unroll
  for (int i = 0; i < 4; i++)
#pragma unroll
    for (int j = 0; j < WNF; j++) acc[i][j] = (floatx4){0.f, 0.f, 0.f, 0.f};

  stage<BM>(A, Bt, rowbase, colbase, K, 0, sA[0], sB[0], tid);
  __syncthreads();   // buf0 ready

  const int NIT = K / 32;
  for (int it = 0; it < NIT; ++it) {
    const int cur = it & 1;
    if (it + 1 < NIT)
      stage<BM>(A, Bt, rowbase, colbase, K, (it + 1) * 32, sA[cur ^ 1], sB[cur ^ 1], tid);
    short8 af[4], bf[WNF];
#pragma unroll
    for (int mt = 0; mt < 4; mt++)
      af[mt] = *(const short8*)(sA[cur] + (wm + mt * 16 + l15) * 32 + q * 8);
#pragma unroll
    for (int nt = 0; nt < WNF; nt++)
      bf[nt] = *(const short8*)(sB[cur] + (wn + nt * 16 + l15) * 32 + q * 8);
#pragma unroll
    for (int mt = 0; mt < 4; mt++)
#pragma unroll
      for (int nt = 0; nt < WNF; nt++)
        acc[mt][nt] = __builtin_amdgcn_mfma_f32_16x16x32_bf16(af[mt], bf[nt], acc[mt][nt], 0, 0, 0);
    if (it + 1 < NIT) __syncthreads();
  }

#pragma unroll
  for (int nt = 0; nt < WNF; nt++) {
    const long col = colbase + wn + nt * 16 + l15;
    const float bv = bias[col];
#pragma unroll
    for (int mt = 0; mt < 4; mt++)
#pragma unroll
      for (int r = 0; r < 4; r++) {
        const long row = rowbase + wm + mt * 16 + q * 4 + r;
        store_out(C + row * N + col, acc[mt][nt][r] + bv);
      }
  }
}

// ---------------------------------------------------------------------------
// Flash attention, causal. One block = (b*12+h, q-tile of 64 rows), 256 thr.
// S^T = K (Q/8)^T formulation: softmax rows live on lane&15 -> in-register
// online softmax (shfl_xor 16/32), no S round-trip, 2 barriers/iter.
// qkv: [8192][2304] bf16 (Q|K|V), y: [8192][768] bf16
// ---------------------------------------------------------------------------
__global__ __launch_bounds__(256) void attn_fwd(
    const u16* __restrict__ qkv, u16* __restrict__ y)
{
  const int bh = blockIdx.x;        // b*12 + h
  const int qt = 15 - blockIdx.y;   // reversed: long blocks dispatch first
  const int b = bh / 12, h = bh % 12;
  const long rowOff = (long)b * 1024;
  const int qb = qt * 64;

  __shared__ __align__(16) u16 sK[64 * 72];
  __shared__ __align__(16) u16 sVs[64 * 72];  // raw V staging [key][d]
  __shared__ __align__(16) u16 sV[64 * 72];   // V^T [d][key]
  __shared__ __align__(16) u16 sP[64 * 72];   // P [qrow][key]

  const int tid = threadIdx.x;
  const int lane = tid & 63, wave = tid >> 6;
  const int l15 = lane & 15, q = lane >> 4;
  const int qrow_g = qb + wave * 16 + l15;    // this lane's softmax row

  // Q fragments in registers, pre-scaled by 1/8 (B-operand: n=l15, k=q*8+j)
  short8 qf[2];
  {
    const u16* qp = qkv + (long)(rowOff + qrow_g) * 2304 + h * 64 + q * 8;
    short8 a0 = *(const short8*)(qp);
    short8 a1 = *(const short8*)(qp + 32);
#pragma unroll
    for (int i = 0; i < 8; i++) {
      a0[i] = (short)f2b(b2f((u16)a0[i]) * 0.125f);
      a1[i] = (short)f2b(b2f((u16)a1[i]) * 0.125f);
    }
    qf[0] = a0; qf[1] = a1;
  }

  float m_i = -1e30f, l_i = 0.f;
  floatx4 o[4];
#pragma unroll
  for (int nt = 0; nt < 4; nt++) o[nt] = (floatx4){0.f, 0.f, 0.f, 0.f};

  for (int j = 0; j <= qt; j++) {
    const int jb = j * 64;
#pragma unroll
    for (int rep = 0; rep < 2; rep++) {
      int idx = tid + rep * 256;
      int r = idx >> 3, ch = (idx & 7) * 8;
      const u16* src = qkv + (long)(rowOff + jb + r) * 2304 + 768 + h * 64 + ch;
      *(short8*)(sK + r * 72 + ch)  = *(const short8*)(src);
      *(short8*)(sVs + r * 72 + ch) = *(const short8*)(src + 768);
    }
    __syncthreads();

    // transpose V: sVs[key][d] -> sV[d][key], packed b64 writes
    {
      int d = tid >> 2, kg = (tid & 3) * 16;
      u16 tmp[16];
#pragma unroll
      for (int i = 0; i < 16; i++) tmp[i] = sVs[(kg + i) * 72 + d];
#pragma unroll
      for (int s = 0; s < 4; s++) {
        short4v vv;
        vv[0] = (short)tmp[s*4]; vv[1] = (short)tmp[s*4+1];
        vv[2] = (short)tmp[s*4+2]; vv[3] = (short)tmp[s*4+3];
        *(short4v*)(sV + d * 72 + kg + s * 4) = vv;
      }
    }

    // S^T = K (Q/8)^T : fragments mt over 16-key blocks
    floatx4 sf[4];
#pragma unroll
    for (int mt = 0; mt < 4; mt++) sf[mt] = (floatx4){0.f, 0.f, 0.f, 0.f};
#pragma unroll
    for (int kk = 0; kk < 2; kk++) {
#pragma unroll
      for (int mt = 0; mt < 4; mt++) {
        short8 kf = *(const short8*)(sK + (mt * 16 + l15) * 72 + kk * 32 + q * 8);
        sf[mt] = __builtin_amdgcn_mfma_f32_16x16x32_bf16(kf, qf[kk], sf[mt], 0, 0, 0);
      }
    }

    // causal mask + in-register online softmax (row = l15-qrow)
    float mx = m_i;
#pragma unroll
    for (int mt = 0; mt < 4; mt++)
#pragma unroll
      for (int r = 0; r < 4; r++) {
        int key_g = jb + mt * 16 + q * 4 + r;
        float v = sf[mt][r];
        if (key_g > qrow_g) v = -1e30f;
        sf[mt][r] = v;
        mx = fmaxf(mx, v);
      }
    mx = fmaxf(mx, __shfl_xor(mx, 16));
    mx = fmaxf(mx, __shfl_xor(mx, 32));
    float al = __expf(m_i - mx);
    m_i = mx;
    float rsum = 0.f;
#pragma unroll
    for (int mt = 0; mt < 4; mt++) {
      short4v pv;
#pragma unroll
      for (int r = 0; r < 4; r++) {
        float p = __expf(sf[mt][r] - mx);
        rsum += p;
        pv[r] = (short)f2b(p);
      }
      *(short4v*)(sP + (wave * 16 + l15) * 72 + mt * 16 + q * 4) = pv;
    }
    rsum += __shfl_xor(rsum, 16);
    rsum += __shfl_xor(rsum, 32);
    l_i = l_i * al + rsum;
    __syncthreads();   // sV + sP visible before PV

    // O = O*alpha + P V   (o rows are q*4+r -> fetch alpha from lane q*4+r)
    float al_r[4];
#pragma unroll
    for (int r = 0; r < 4; r++) al_r[r] = __shfl(al, q * 4 + r);
#pragma unroll
    for (int nt = 0; nt < 4; nt++)
#pragma unroll
      for (int r = 0; r < 4; r++) o[nt][r] *= al_r[r];
#pragma unroll
    for (int kk = 0; kk < 2; kk++) {
      short8 pf = *(const short8*)(sP + (wave * 16 + l15) * 72 + kk * 32 + q * 8);
#pragma unroll
      for (int nt = 0; nt < 4; nt++) {
        short8 vf = *(const short8*)(sV + (nt * 16 + l15) * 72 + kk * 32 + q * 8);
        o[nt] = __builtin_amdgcn_mfma_f32_16x16x32_bf16(pf, vf, o[nt], 0, 0, 0);
      }
    }
  }

  float linv = 1.f / l_i;
  float li_r[4];
#pragma unroll
  for (int r = 0; r < 4; r++) li_r[r] = __shfl(linv, q * 4 + r);
#pragma unroll
  for (int nt = 0; nt < 4; nt++)
#pragma unroll
    for (int r = 0; r < 4; r++) {
      int row = qb + wave * 16 + q * 4 + r;
      int col = h * 64 + nt * 16 + l15;
      y[(rowOff + row) * 768 + col] = f2b(o[nt][r] * li_r[r]);
    }
}

// ---------------------------------------------------------------------------
extern "C" void kernel_launch(void* const* d_in, const int* in_sizes, int n_in,
                              void* d_out, int out_size, void* d_ws, size_t ws_size,
                              hipStream_t stream) {
  const float* x      = (const float*)d_in[0];  // [8192][768] fp32
  const float* w_attn = (const float*)d_in[1];  // [768][2304] fp32
  const float* b_attn = (const float*)d_in[2];  // [2304] fp32
  const float* w_proj = (const float*)d_in[3];  // [768][768] fp32
  const float* b_proj = (const float*)d_in[4];  // [768] fp32
  float* out = (float*)d_out;                   // [8192][768] fp32

  char* ws = (char*)d_ws;
  u16* xb   = (u16*)ws; ws += (size_t)8192 * 768 * 2;    // 12.6 MB
  u16* wTa  = (u16*)ws; ws += (size_t)2304 * 768 * 2;    //  3.5 MB
  u16* wTp  = (u16*)ws; ws += (size_t)768 * 768 * 2;     //  1.2 MB
  u16* qkv  = (u16*)ws; ws += (size_t)8192 * 2304 * 2;   // 37.7 MB
  u16* yatt = (u16*)ws; ws += (size_t)8192 * 768 * 2;    // 12.6 MB

  // fused prep: x->bf16 + both weight transposes
  prep<<<dim3(6720), 256, 0, stream>>>(x, xb, w_attn, wTa, w_proj, wTp);

  // qkv = x @ w_attn + b_attn   (bf16 out, 128x128 tiles, XCD swizzle)
  gemm_bt_bias<u16, 128><<<dim3(18 * 64), 256, 0, stream>>>(xb, wTa, b_attn, qkv, 8192, 2304, 768, 18);

  // flash attention (in-register softmax)
  attn_fwd<<<dim3(96, 16), 256, 0, stream>>>(qkv, yatt);

  // out = yatt @ w_proj + b_proj   (fp32 out, 64x128 tiles, XCD swizzle)
  gemm_bt_bias<float, 64><<<dim3(6 * 128), 256, 0, stream>>>(yatt, wTp, b_proj, out, 8192, 768, 768, 6);
}

// Round 8
// 211.558 us; speedup vs baseline: 1.0627x; 1.0453x over previous
//
#include <hip/hip_runtime.h>
#include <hip/hip_bf16.h>
#include <stdint.h>

typedef unsigned short u16;
typedef short short8 __attribute__((ext_vector_type(8)));
typedef short short4v __attribute__((ext_vector_type(4)));
typedef float floatx4 __attribute__((ext_vector_type(4)));

__device__ __forceinline__ float b2f(u16 v) {
  union { unsigned int u; float f; } c; c.u = ((unsigned int)v) << 16; return c.f;
}
__device__ __forceinline__ u16 f2b(float f) {
  union { float f; unsigned int u; } c; c.f = f;
  unsigned int u = c.u;
  return (u16)((u + 0x7fffu + ((u >> 16) & 1u)) >> 16);  // RNE
}

// async global->LDS, 16B per lane. LDS dest must be wave-uniform base + lane*16.
__device__ __forceinline__ void gld_lds16(const u16* g, u16* l) {
  __builtin_amdgcn_global_load_lds(
      (const __attribute__((address_space(1))) unsigned int*)g,
      (__attribute__((address_space(3))) unsigned int*)l,
      16, 0, 0);
}

// ---------------------------------------------------------------------------
// Fused prep: x fp32->bf16 (blocks 0..6143), w_attn T (6144..6575),
// w_proj T (6576..6719). Transposes also convert fp32->bf16.
// ---------------------------------------------------------------------------
__device__ __forceinline__ void tile_transpose_f2b(
    const float* __restrict__ in, u16* __restrict__ out,
    int inRS, int outRS, int rb, int cb, int tid)
{
  __shared__ __align__(16) u16 t[64][72];
  const int r = tid >> 2, sg = tid & 3;
  const float* ip = in + (long)(rb + r) * inRS + cb + sg * 16;
#pragma unroll
  for (int i = 0; i < 16; i += 4) {
    float4 f = *(const float4*)(ip + i);
    t[r][sg * 16 + i]     = f2b(f.x);
    t[r][sg * 16 + i + 1] = f2b(f.y);
    t[r][sg * 16 + i + 2] = f2b(f.z);
    t[r][sg * 16 + i + 3] = f2b(f.w);
  }
  __syncthreads();
  short8 v0, v1;
#pragma unroll
  for (int i = 0; i < 8; i++) v0[i] = (short)t[sg * 16 + i][r];
#pragma unroll
  for (int i = 0; i < 8; i++) v1[i] = (short)t[sg * 16 + 8 + i][r];
  *(short8*)(out + (long)(cb + r) * outRS + rb + sg * 16)     = v0;
  *(short8*)(out + (long)(cb + r) * outRS + rb + sg * 16 + 8) = v1;
}

__global__ __launch_bounds__(256) void prep(
    const float* __restrict__ x, u16* __restrict__ xb,
    const float* __restrict__ w_attn, u16* __restrict__ wTa,
    const float* __restrict__ w_proj, u16* __restrict__ wTp)
{
  const int bid = blockIdx.x, tid = threadIdx.x;
  if (bid < 6144) {
    int i = (bid * 256 + tid) * 4;
    float4 f = *(const float4*)(x + i);
    short4v v;
    v[0] = (short)f2b(f.x); v[1] = (short)f2b(f.y);
    v[2] = (short)f2b(f.z); v[3] = (short)f2b(f.w);
    *(short4v*)(xb + i) = v;
  } else if (bid < 6576) {
    int t = bid - 6144;                 // 36 x 12 tiles of w_attn [768][2304]
    tile_transpose_f2b(w_attn, wTa, 2304, 768, (t / 36) * 64, (t % 36) * 64, tid);
  } else {
    int t = bid - 6576;                 // 12 x 12 tiles of w_proj [768][768]
    tile_transpose_f2b(w_proj, wTp, 768, 768, (t / 12) * 64, (t % 12) * 64, tid);
  }
}

// ---------------------------------------------------------------------------
// C = A * Bt^T + bias  (A,Bt bf16, fp32 accum). R5 double-buffer (measured
// best; raw-vmcnt pipeline R6 and XCD swizzle R7 both regressed).
// SPLIT (qkv GEMM): col tiles <1536 -> qk[row][1536] bf16;
//                   col tiles >=1536 (V) -> vT[b*12+h][d][t] bf16 (transposed
//                   here so attn needs no per-iter LDS transpose).
// ---------------------------------------------------------------------------
__device__ __forceinline__ void store_out(u16* p, float v)  { *p = f2b(v); }
__device__ __forceinline__ void store_out(float* p, float v) { *p = v; }

template <int BM>
__device__ __forceinline__ void stage(
    const u16* __restrict__ A, const u16* __restrict__ Bt,
    long rowbase, long colbase, int K, int k0,
    u16* dA, u16* dB, int tid)
{
  const int c0 = tid, c1 = tid + 256;
  const int ar0 = c0 >> 2, ak0 = (c0 & 3) * 8;
  const int ar1 = c1 >> 2, ak1 = (c1 & 3) * 8;
  gld_lds16(A + (rowbase + ar0) * K + k0 + ak0, dA + c0 * 8);
  if (BM == 128)
    gld_lds16(A + (rowbase + ar1) * K + k0 + ak1, dA + c1 * 8);
  gld_lds16(Bt + (colbase + ar0) * K + k0 + ak0, dB + c0 * 8);
  gld_lds16(Bt + (colbase + ar1) * K + k0 + ak1, dB + c1 * 8);
}

template <typename OT, int BM, bool SPLIT>
__global__ __launch_bounds__(256) void gemm_bt_bias(
    const u16* __restrict__ A, const u16* __restrict__ Bt,
    const float* __restrict__ bias, OT* __restrict__ C, u16* __restrict__ vT,
    int M, int N, int K, int strideC)
{
  constexpr int WNF = (BM == 128) ? 4 : 2;      // n-frags per wave
  __shared__ __align__(16) u16 sA[2][BM * 32];
  __shared__ __align__(16) u16 sB[2][128 * 32];
  const int tid = threadIdx.x;
  const int lane = tid & 63;
  const int wave = tid >> 6;
  const int wm = (BM == 128) ? (wave >> 1) * 64 : 0;
  const int wn = (BM == 128) ? (wave & 1) * 64 : wave * 32;
  const int l15 = lane & 15;
  const int q = lane >> 4;
  const long rowbase = (long)blockIdx.y * BM;
  const long colbase = (long)blockIdx.x * 128;

  floatx4 acc[4][WNF];
#pragma unroll
  for (int i = 0; i < 4; i++)
#pragma unroll
    for (int j = 0; j < WNF; j++) acc[i][j] = (floatx4){0.f, 0.f, 0.f, 0.f};

  stage<BM>(A, Bt, rowbase, colbase, K, 0, sA[0], sB[0], tid);
  __syncthreads();   // buf0 ready

  const int NIT = K / 32;
  for (int it = 0; it < NIT; ++it) {
    const int cur = it & 1;
    if (it + 1 < NIT)
      stage<BM>(A, Bt, rowbase, colbase, K, (it + 1) * 32, sA[cur ^ 1], sB[cur ^ 1], tid);
    short8 af[4], bf[WNF];
#pragma unroll
    for (int mt = 0; mt < 4; mt++)
      af[mt] = *(const short8*)(sA[cur] + (wm + mt * 16 + l15) * 32 + q * 8);
#pragma unroll
    for (int nt = 0; nt < WNF; nt++)
      bf[nt] = *(const short8*)(sB[cur] + (wn + nt * 16 + l15) * 32 + q * 8);
#pragma unroll
    for (int mt = 0; mt < 4; mt++)
#pragma unroll
      for (int nt = 0; nt < WNF; nt++)
        acc[mt][nt] = __builtin_amdgcn_mfma_f32_16x16x32_bf16(af[mt], bf[nt], acc[mt][nt], 0, 0, 0);
    if (it + 1 < NIT) __syncthreads();
  }

  if (SPLIT && colbase >= 1536) {
    // V region -> vT[b*12+h][d][t], packed 4-row (t-consecutive) stores
    const long b = rowbase >> 10;
    const int t0b = (int)(rowbase & 1023) + wm;
#pragma unroll
    for (int nt = 0; nt < WNF; nt++) {
      const int col = (int)colbase + wn + nt * 16 + l15;
      const float bv = bias[col];
      const int dloc = col - 1536;
      u16* bp = vT + (b * 12 + (dloc >> 6)) * 65536L + (long)(dloc & 63) * 1024;
#pragma unroll
      for (int mt = 0; mt < 4; mt++) {
        short4v pv;
#pragma unroll
        for (int r = 0; r < 4; r++) pv[r] = (short)f2b(acc[mt][nt][r] + bv);
        *(short4v*)(bp + t0b + mt * 16 + q * 4) = pv;
      }
    }
  } else {
#pragma unroll
    for (int nt = 0; nt < WNF; nt++) {
      const long col = colbase + wn + nt * 16 + l15;
      const float bv = bias[col];
#pragma unroll
      for (int mt = 0; mt < 4; mt++)
#pragma unroll
        for (int r = 0; r < 4; r++) {
          const long row = rowbase + wm + mt * 16 + q * 4 + r;
          store_out(C + row * strideC + col, acc[mt][nt][r] + bv);
        }
    }
  }
}

// ---------------------------------------------------------------------------
// Flash attention, causal. One block = (b*12+h, q-tile of 64 rows), 256 thr.
// S^T = K (Q/8)^T: in-register online softmax (shfl_xor 16/32).
// V arrives pre-transposed from the qkv GEMM (vT) -> no in-LDS transpose.
// sV double-buffered: staging(j) writes sV[j&1] while PV(j-1) reads sV[~j&1].
// qk: [8192][1536] bf16 (Q|K), vT: [96][64][1024] bf16, y: [8192][768] bf16
// ---------------------------------------------------------------------------
__global__ __launch_bounds__(256) void attn_fwd(
    const u16* __restrict__ qk, const u16* __restrict__ vT, u16* __restrict__ y)
{
  const int bh = blockIdx.x;        // b*12 + h
  const int qt = 15 - blockIdx.y;   // reversed: long blocks dispatch first
  const int b = bh / 12, h = bh % 12;
  const long rowOff = (long)b * 1024;
  const int qb = qt * 64;

  __shared__ __align__(16) u16 sK[64 * 72];
  __shared__ __align__(16) u16 sV[2][64 * 72];  // V^T [d][key], double-buffered
  __shared__ __align__(16) u16 sP[64 * 72];     // P [qrow][key]

  const int tid = threadIdx.x;
  const int lane = tid & 63, wave = tid >> 6;
  const int l15 = lane & 15, q = lane >> 4;
  const int qrow_g = qb + wave * 16 + l15;    // this lane's softmax row

  // Q fragments in registers, pre-scaled by 1/8 (B-operand: n=l15, k=q*8+j)
  short8 qf[2];
  {
    const u16* qp = qk + (long)(rowOff + qrow_g) * 1536 + h * 64 + q * 8;
    short8 a0 = *(const short8*)(qp);
    short8 a1 = *(const short8*)(qp + 32);
#pragma unroll
    for (int i = 0; i < 8; i++) {
      a0[i] = (short)f2b(b2f((u16)a0[i]) * 0.125f);
      a1[i] = (short)f2b(b2f((u16)a1[i]) * 0.125f);
    }
    qf[0] = a0; qf[1] = a1;
  }

  float m_i = -1e30f, l_i = 0.f;
  floatx4 o[4];
#pragma unroll
  for (int nt = 0; nt < 4; nt++) o[nt] = (floatx4){0.f, 0.f, 0.f, 0.f};

  for (int j = 0; j <= qt; j++) {
    const int jb = j * 64;
    u16* sVc = sV[j & 1];
#pragma unroll
    for (int rep = 0; rep < 2; rep++) {
      int idx = tid + rep * 256;
      int r = idx >> 3, ch = (idx & 7) * 8;
      *(short8*)(sK + r * 72 + ch) =
          *(const short8*)(qk + (long)(rowOff + jb + r) * 1536 + 768 + h * 64 + ch);
      *(short8*)(sVc + r * 72 + ch) =
          *(const short8*)(vT + (long)bh * 65536 + (long)r * 1024 + jb + ch);
    }
    __syncthreads();

    // S^T = K (Q/8)^T : fragments mt over 16-key blocks
    floatx4 sf[4];
#pragma unroll
    for (int mt = 0; mt < 4; mt++) sf[mt] = (floatx4){0.f, 0.f, 0.f, 0.f};
#pragma unroll
    for (int kk = 0; kk < 2; kk++) {
#pragma unroll
      for (int mt = 0; mt < 4; mt++) {
        short8 kf = *(const short8*)(sK + (mt * 16 + l15) * 72 + kk * 32 + q * 8);
        sf[mt] = __builtin_amdgcn_mfma_f32_16x16x32_bf16(kf, qf[kk], sf[mt], 0, 0, 0);
      }
    }

    // causal mask + in-register online softmax (row = l15-qrow)
    float mx = m_i;
#pragma unroll
    for (int mt = 0; mt < 4; mt++)
#pragma unroll
      for (int r = 0; r < 4; r++) {
        int key_g = jb + mt * 16 + q * 4 + r;
        float v = sf[mt][r];
        if (key_g > qrow_g) v = -1e30f;
        sf[mt][r] = v;
        mx = fmaxf(mx, v);
      }
    mx = fmaxf(mx, __shfl_xor(mx, 16));
    mx = fmaxf(mx, __shfl_xor(mx, 32));
    float al = __expf(m_i - mx);
    m_i = mx;
    float rsum = 0.f;
#pragma unroll
    for (int mt = 0; mt < 4; mt++) {
      short4v pv;
#pragma unroll
      for (int r = 0; r < 4; r++) {
        float p = __expf(sf[mt][r] - mx);
        rsum += p;
        pv[r] = (short)f2b(p);
      }
      *(short4v*)(sP + (wave * 16 + l15) * 72 + mt * 16 + q * 4) = pv;
    }
    rsum += __shfl_xor(rsum, 16);
    rsum += __shfl_xor(rsum, 32);
    l_i = l_i * al + rsum;
    __syncthreads();   // sP (+ this iter's sV) visible before PV

    // O = O*alpha + P V   (o rows are q*4+r -> fetch alpha from lane q*4+r)
    float al_r[4];
#pragma unroll
    for (int r = 0; r < 4; r++) al_r[r] = __shfl(al, q * 4 + r);
#pragma unroll
    for (int nt = 0; nt < 4; nt++)
#pragma unroll
      for (int r = 0; r < 4; r++) o[nt][r] *= al_r[r];
#pragma unroll
    for (int kk = 0; kk < 2; kk++) {
      short8 pf = *(const short8*)(sP + (wave * 16 + l15) * 72 + kk * 32 + q * 8);
#pragma unroll
      for (int nt = 0; nt < 4; nt++) {
        short8 vf = *(const short8*)(sVc + (nt * 16 + l15) * 72 + kk * 32 + q * 8);
        o[nt] = __builtin_amdgcn_mfma_f32_16x16x32_bf16(pf, vf, o[nt], 0, 0, 0);
      }
    }
  }

  float linv = 1.f / l_i;
  float li_r[4];
#pragma unroll
  for (int r = 0; r < 4; r++) li_r[r] = __shfl(linv, q * 4 + r);
#pragma unroll
  for (int nt = 0; nt < 4; nt++)
#pragma unroll
    for (int r = 0; r < 4; r++) {
      int row = qb + wave * 16 + q * 4 + r;
      int col = h * 64 + nt * 16 + l15;
      y[(rowOff + row) * 768 + col] = f2b(o[nt][r] * li_r[r]);
    }
}

// ---------------------------------------------------------------------------
extern "C" void kernel_launch(void* const* d_in, const int* in_sizes, int n_in,
                              void* d_out, int out_size, void* d_ws, size_t ws_size,
                              hipStream_t stream) {
  const float* x      = (const float*)d_in[0];  // [8192][768] fp32
  const float* w_attn = (const float*)d_in[1];  // [768][2304] fp32
  const float* b_attn = (const float*)d_in[2];  // [2304] fp32
  const float* w_proj = (const float*)d_in[3];  // [768][768] fp32
  const float* b_proj = (const float*)d_in[4];  // [768] fp32
  float* out = (float*)d_out;                   // [8192][768] fp32

  char* ws = (char*)d_ws;
  u16* xb   = (u16*)ws; ws += (size_t)8192 * 768 * 2;     // 12.6 MB
  u16* wTa  = (u16*)ws; ws += (size_t)2304 * 768 * 2;     //  3.5 MB
  u16* wTp  = (u16*)ws; ws += (size_t)768 * 768 * 2;      //  1.2 MB
  u16* qk   = (u16*)ws; ws += (size_t)8192 * 1536 * 2;    // 25.2 MB (Q|K)
  u16* vT   = (u16*)ws; ws += (size_t)96 * 64 * 1024 * 2; // 12.6 MB (V^T)
  u16* yatt = (u16*)ws; ws += (size_t)8192 * 768 * 2;     // 12.6 MB
  // total 67.6 MB (same as R5-R7, known-good)

  // fused prep: x->bf16 + both weight transposes
  prep<<<dim3(6720), 256, 0, stream>>>(x, xb, w_attn, wTa, w_proj, wTp);

  // qkv GEMM: Q|K -> qk (strided), V -> vT (transposed in epilogue)
  gemm_bt_bias<u16, 128, true><<<dim3(18, 64), 256, 0, stream>>>(
      xb, wTa, b_attn, qk, vT, 8192, 2304, 768, 1536);

  // flash attention (V pre-transposed; in-register softmax)
  attn_fwd<<<dim3(96, 16), 256, 0, stream>>>(qk, vT, yatt);

  // out = yatt @ w_proj + b_proj   (fp32 out, 64x128 tiles)
  gemm_bt_bias<float, 64, false><<<dim3(6, 128), 256, 0, stream>>>(
      yatt, wTp, b_proj, out, (u16*)nullptr, 8192, 768, 768, 768);
}